// Round 7
// baseline (850.581 us; speedup 1.0000x reference)
//
#include <hip/hip_runtime.h>
#include <cstdint>
#include <cstddef>

// B=10, Hi=Wi=64, C=64, M=8, Hb=Wb=128, U=64.
// conv1 = fp32-accurate MFMA implicit GEMM via 3-way bf16 split (6 products).
// New in this round: inputs pre-split into zero-padded bf16 planes; conv1 is
// a no-LDS register-tiled kernel (wave = 64px x 64u, 4x4 fragment tile) with
// in-register A/B reuse; L1 serves the halo overlap. h1 stays fp32 (rmask
// accuracy cliff). conv2 / compose unchanged (proven).

typedef __attribute__((ext_vector_type(8))) short short8;
typedef __attribute__((ext_vector_type(4))) float f32x4;

__device__ __forceinline__ unsigned short f2bf(float x) {
  union { float f; unsigned int u; } v; v.f = x;
  unsigned int r = (v.u + 0x7FFFu + ((v.u >> 16) & 1u)) >> 16;  // RNE
  return (unsigned short)r;
}
__device__ __forceinline__ float bf2f(unsigned short h) {
  union { unsigned int u; float f; } v; v.u = ((unsigned int)h) << 16;
  return v.f;
}
__device__ __forceinline__ void split3(float v, unsigned short& h,
                                       unsigned short& m, unsigned short& l) {
  h = f2bf(v);
  float r1 = v - bf2f(h);
  m = f2bf(r1);
  float r2 = r1 - bf2f(m);
  l = f2bf(r2);
}

// ---------------------------------------------------------------------------
// prep_w3: w [3,3,64,64] HWIO fp32 -> 3 bf16 fragment-ordered planes (36864
// elems apart): wB[s][((kc*4+ut)*64+lane)*8+i], k=kc*32+(lane>>4)*8+i,
// k9=k>>6, c=k&63, u=ut*16+(lane&15).  (verified in rounds 5/6)
// ---------------------------------------------------------------------------
__global__ void prep_w3(const float* __restrict__ w, unsigned short* __restrict__ wB)
{
  int idx = blockIdx.x * 256 + threadIdx.x;
  if (idx >= 18 * 4 * 64 * 8) return;
  int i = idx & 7;
  int lane = (idx >> 3) & 63;
  int ut = (idx >> 9) & 3;
  int kc = idx >> 11;
  int k = kc * 32 + (lane >> 4) * 8 + i;
  int u = ut * 16 + (lane & 15);
  int k9 = k >> 6, c = k & 63;
  float v = w[((size_t)(k9 * 64 + c)) * 64 + u];
  unsigned short h, m, l;
  split3(v, h, m, l);
  wB[idx] = h;
  wB[36864 + idx] = m;
  wB[73728 + idx] = l;
}

// ---------------------------------------------------------------------------
// split_inst: IF chunk (nb b's) -> padded bf16 planes T[img][66][66][64],
// img = bb*8+m. Thread = (bb,yp,xp,c), reads 8 m contiguously (32 B), writes
// 24 bf16 (wave-coalesced 128-B segments per (m,plane)). Borders -> 0.
// ---------------------------------------------------------------------------
__global__ __launch_bounds__(256) void split_inst(const float* __restrict__ IFc,
    unsigned short* __restrict__ T, unsigned int PS, int nb)
{
  const int e = blockIdx.x * 256 + threadIdx.x;      // nb*66*66*64
  const int c = e & 63;
  const int q = e >> 6;
  const int xp = q % 66;
  const int q2 = q / 66;
  const int yp = q2 % 66;
  const int bb = q2 / 66;
  if (bb >= nb) return;

  float v[8] = {0.f, 0.f, 0.f, 0.f, 0.f, 0.f, 0.f, 0.f};
  if (yp >= 1 && yp <= 64 && xp >= 1 && xp <= 64) {
    const float* p = IFc + ((((size_t)bb * 64 + (yp - 1)) * 64 + (xp - 1)) * 64 + c) * 8;
    float4 a = *(const float4*)p;
    float4 b = *(const float4*)(p + 4);
    v[0] = a.x; v[1] = a.y; v[2] = a.z; v[3] = a.w;
    v[4] = b.x; v[5] = b.y; v[6] = b.z; v[7] = b.w;
  }
  #pragma unroll
  for (int m = 0; m < 8; ++m) {
    unsigned short h, mi, l;
    split3(v[m], h, mi, l);
    size_t di = ((size_t)(bb * 8 + m) * 4356 + yp * 66 + xp) * 64 + c;
    T[di] = h;
    T[(size_t)PS + di] = mi;
    T[(size_t)2 * PS + di] = l;
  }
}

// ---------------------------------------------------------------------------
// split_bg: BG chunk (ng imgs) -> padded planes T[img][130][130][64].
// ---------------------------------------------------------------------------
__global__ __launch_bounds__(256) void split_bg(const float* __restrict__ BGc,
    unsigned short* __restrict__ T, unsigned int PS, int ng)
{
  const int e = blockIdx.x * 256 + threadIdx.x;      // ng*130*130*64
  const int c = e & 63;
  const int q = e >> 6;
  const int xp = q % 130;
  const int q2 = q / 130;
  const int yp = q2 % 130;
  const int ii = q2 / 130;
  if (ii >= ng) return;

  float v = 0.f;
  if (yp >= 1 && yp <= 128 && xp >= 1 && xp <= 128)
    v = BGc[(((size_t)ii * 128 + (yp - 1)) * 128 + (xp - 1)) * 64 + c];
  unsigned short h, mi, l;
  split3(v, h, mi, l);
  size_t di = ((size_t)ii * 16900 + yp * 130 + xp) * 64 + c;
  T[di] = h;
  T[(size_t)PS + di] = mi;
  T[(size_t)2 * PS + di] = l;
}

// ---------------------------------------------------------------------------
// conv1_dg: padded bf16 planes -> fp32 h1 [N,H,W,64], 3x3 SAME + bias + relu.
// No LDS, no barriers. Block = 4 waves = 4 consecutive output rows; wave =
// 64 px x 64 u (4 px-tiles x 4 u-tiles). A direct from padded planes (halo
// via padding), B fragment-ordered from wB (L2-resident); A reused across
// ut, B reused across pxt in registers. 6-product split accumulation.
// MFMA conventions identical to the round-6-verified kernel.
// ---------------------------------------------------------------------------
__global__ __launch_bounds__(256) void conv1_dg(const unsigned short* __restrict__ T,
    unsigned int PS, const unsigned short* __restrict__ wB,
    const float* __restrict__ bias, float* __restrict__ H1,
    int H, int W, int Hp, int Wp)
{
  const int tilesX = W >> 6;
  const int bid = blockIdx.x;
  const int xt = bid % tilesX;
  const int t2 = bid / tilesX;
  const int rg = t2 % (H >> 2);
  const int img = t2 / (H >> 2);
  const int wave = threadIdx.x >> 6, lane = threadIdx.x & 63;
  const int y = rg * 4 + wave;
  const int xb = xt << 6;
  const int mrow = lane & 15, g = lane >> 4;

  f32x4 z = {0.f, 0.f, 0.f, 0.f};
  f32x4 acc[4][4];
  #pragma unroll
  for (int i = 0; i < 4; ++i)
    #pragma unroll
    for (int j = 0; j < 4; ++j)
      acc[i][j] = z;

  const short8* wBp = (const short8*)wB;

  for (int tap = 0; tap < 9; ++tap) {
    const int dy = tap / 3, dx = tap % 3;
    // padded row for input row (y+dy-1) is (y+dy); padded x for (x+dx-1) is x+dx
    const unsigned short* rowp =
        T + (((size_t)img * Hp + (y + dy)) * Wp + (xb + mrow + dx)) * 64 + g * 8;
    #pragma unroll
    for (int chh = 0; chh < 2; ++chh) {
      short8 a[4][3];
      #pragma unroll
      for (int pxt = 0; pxt < 4; ++pxt)
        #pragma unroll
        for (int pl = 0; pl < 3; ++pl)
          a[pxt][pl] = *(const short8*)(rowp + (size_t)pl * PS + pxt * 1024 + chh * 32);
      const int kc = tap * 2 + chh;
      #pragma unroll
      for (int ut = 0; ut < 4; ++ut) {
        const int bi = (kc * 4 + ut) * 64 + lane;
        short8 bh = wBp[bi];
        short8 bm = wBp[4608 + bi];
        short8 bl = wBp[9216 + bi];
        #pragma unroll
        for (int pxt = 0; pxt < 4; ++pxt) {
          f32x4 v = acc[pxt][ut];
          v = __builtin_amdgcn_mfma_f32_16x16x32_bf16(a[pxt][0], bh, v, 0, 0, 0);
          v = __builtin_amdgcn_mfma_f32_16x16x32_bf16(a[pxt][0], bm, v, 0, 0, 0);
          v = __builtin_amdgcn_mfma_f32_16x16x32_bf16(a[pxt][1], bh, v, 0, 0, 0);
          v = __builtin_amdgcn_mfma_f32_16x16x32_bf16(a[pxt][0], bl, v, 0, 0, 0);
          v = __builtin_amdgcn_mfma_f32_16x16x32_bf16(a[pxt][2], bh, v, 0, 0, 0);
          v = __builtin_amdgcn_mfma_f32_16x16x32_bf16(a[pxt][1], bm, v, 0, 0, 0);
          acc[pxt][ut] = v;
        }
      }
    }
  }

  // D: row = (lane>>4)*4 + r (= px within 16-tile), col = lane&15 (= u)
  #pragma unroll
  for (int ut = 0; ut < 4; ++ut) {
    const int u = ut * 16 + mrow;
    const float bv = bias[u];
    #pragma unroll
    for (int pxt = 0; pxt < 4; ++pxt) {
      #pragma unroll
      for (int r = 0; r < 4; ++r) {
        const int px = xb + pxt * 16 + g * 4 + r;
        H1[((size_t)(img * H + y) * W + px) * 64 + u] = fmaxf(acc[pxt][ut][r] + bv, 0.f);
      }
    }
  }
}

// ---------------------------------------------------------------------------
// conv2: 3x3 SAME, 64 -> 1 ch + bias + relu, fp32 (proven).
// ---------------------------------------------------------------------------
__global__ __launch_bounds__(256) void conv2_k(const float* __restrict__ hsrc,
    const float* __restrict__ w2, const float* __restrict__ b2,
    float* __restrict__ dst, int N, int H, int W)
{
  const int RS = 24;
  const int CS = 18 * 24 + 1;  // 433
  __shared__ float s[32 * (18 * 24 + 1)];
  __shared__ float wsm[576];

  const int tid = threadIdx.x;
  const int tilesX = W >> 4;
  const int bid = blockIdx.x;
  const int xt = bid % tilesX;
  const int q0 = bid / tilesX;
  const int yt = q0 % (H >> 4);
  const int n = q0 / (H >> 4);
  const int xb = xt << 4, yb = yt << 4;
  const int tx = tid & 15, ty = tid >> 4;

  for (int e = tid; e < 576; e += 256) wsm[e] = w2[e];

  float acc = 0.f;
  for (int cc = 0; cc < 2; ++cc) {
    const int c0 = cc << 5;
    if (cc) __syncthreads();
    for (int e = tid; e < 18 * 18 * 32; e += 256) {
      int c = e & 31;
      int p = e >> 5;
      int xx = p % 18;
      int yy = p / 18;
      int gy = yb + yy - 1, gx = xb + xx - 1;
      float v = 0.f;
      if (gy >= 0 && gy < H && gx >= 0 && gx < W)
        v = hsrc[((size_t)(n * H + gy) * W + gx) * 64 + c0 + c];
      s[c * CS + yy * RS + xx] = v;
    }
    __syncthreads();
    for (int c = 0; c < 32; ++c) {
      const float* sp = &s[c * CS + ty * RS + tx];
      const float* wp = &wsm[c0 + c];
      #pragma unroll
      for (int dy = 0; dy < 3; ++dy)
        #pragma unroll
        for (int dx = 0; dx < 3; ++dx)
          acc += sp[dy * RS + dx] * wp[(dy * 3 + dx) * 64];
    }
  }
  float bv = b2[0];
  dst[((size_t)n * H + yb + ty) * W + xb + tx] = fmaxf(acc + bv, 0.f);
}

// ---------------------------------------------------------------------------
// compose: fused resize_and_pad + masked-exp softmax composition (proven).
// ---------------------------------------------------------------------------
__global__ __launch_bounds__(256) void compose_k(const float* __restrict__ IF,
    const float* __restrict__ bg, const float* __restrict__ bbox,
    const int* __restrict__ objn, const float* __restrict__ instw,
    const float* __restrict__ bgw, float* __restrict__ out)
{
  const int tid = threadIdx.x;
  const int c = tid & 63;
  const int pid = blockIdx.x * 4 + (tid >> 6);
  const int b = pid >> 14;
  const int rem = pid & 16383;
  const int hh = rem >> 7;
  const int www = rem & 127;

  const float ebg = expf(bgw[pid]);
  const float bgc = bg[(size_t)pid * 64 + c];
  float acc = ebg * bgc;
  float denom = ebg;
  const int nobj = objn[b];

  #pragma unroll
  for (int m = 0; m < 8; ++m) {
    if (m >= nobj) continue;
    const float y0b = bbox[b * 32 + m];
    const float y1b = bbox[b * 32 + 8 + m];
    const float x0b = bbox[b * 32 + 16 + m];
    const float x1b = bbox[b * 32 + 24 + m];
    const float ysz = floorf(128.f * (y1b - y0b));
    const float xsz = floorf(128.f * (x1b - x0b));
    const float yf = floorf(128.f * y0b);
    const float xf = floorf(128.f * x0b);
    const float ly = (float)hh - yf;
    const float lx = (float)www - xf;
    if (!(ly >= 0.f && ly < ysz && lx >= 0.f && lx < xsz)) continue;
    float sy = (ly + 0.5f) * 64.f / fmaxf(ysz, 1.f) - 0.5f;
    float sx = (lx + 0.5f) * 64.f / fmaxf(xsz, 1.f) - 0.5f;
    sy = fminf(fmaxf(sy, 0.f), 63.f);
    sx = fminf(fmaxf(sx, 0.f), 63.f);
    const int y0i = (int)floorf(sy);
    const int x0i = (int)floorf(sx);
    const int y1i = min(y0i + 1, 63);
    const int x1i = min(x0i + 1, 63);
    const float wy = sy - (float)y0i;
    const float wx = sx - (float)x0i;
    const float omwx = 1.f - wx, omwy = 1.f - wy;

    const float* iw = instw + (size_t)(b * 8 + m) * 4096;
    const float v00 = iw[y0i * 64 + x0i];
    const float v01 = iw[y0i * 64 + x1i];
    const float v10 = iw[y1i * 64 + x0i];
    const float v11 = iw[y1i * 64 + x1i];
    const float rwv = (v00 * omwx + v01 * wx) * omwy + (v10 * omwx + v11 * wx) * wy;
    if (!(rwv > 0.f)) continue;
    const float e = expf(rwv);
    denom += e;

    const float* fb = IF + (size_t)b * 2097152 + (size_t)c * 8 + m;
    const float t00 = fb[(size_t)y0i * 32768 + (size_t)x0i * 512];
    const float t01 = fb[(size_t)y0i * 32768 + (size_t)x1i * 512];
    const float t10 = fb[(size_t)y1i * 32768 + (size_t)x0i * 512];
    const float t11 = fb[(size_t)y1i * 32768 + (size_t)x1i * 512];
    const float bil = (t00 * omwx + t01 * wx) * omwy + (t10 * omwx + t11 * wx) * wy;
    acc += e * bil;
  }
  out[(size_t)pid * 64 + c] = acc / denom;
}

// ---------------------------------------------------------------------------
extern "C" void kernel_launch(void* const* d_in, const int* in_sizes, int n_in,
                              void* d_out, int out_size, void* d_ws, size_t ws_size,
                              hipStream_t stream)
{
  const float* IF   = (const float*)d_in[0];   // [10,64,64,64,8]
  const float* BG   = (const float*)d_in[1];   // [10,128,128,64]
  const float* BBOX = (const float*)d_in[2];   // [10,4,8]
  const float* w1i = (const float*)d_in[4];
  const float* b1i = (const float*)d_in[5];
  const float* w2i = (const float*)d_in[6];
  const float* b2i = (const float*)d_in[7];
  const float* w1b = (const float*)d_in[8];
  const float* b1b = (const float*)d_in[9];
  const float* w2b = (const float*)d_in[10];
  const float* b2b = (const float*)d_in[11];
  const int* objn  = (const int*)d_in[12];
  float* out = (float*)d_out;

  // ---- fixed region
  char* wsb = (char*)d_ws;
  unsigned short* wBi3 = (unsigned short*)(wsb);              // 221,184 B
  unsigned short* wBb3 = (unsigned short*)(wsb + 221184);     // 221,184 B
  float* instw = (float*)(wsb + 442368);                      // 1,310,720 B
  float* bgw   = (float*)(wsb + 1753088);                     // 655,360 B
  const size_t fixed_end = 2408448;                           // 256-aligned

  // ---- adaptive chunking (ws_size-driven, deterministic)
  const size_t costTb = 13381632, costH1b = 8388608;   // per instance-b (8 imgs)
  const size_t costTg = 6489600,  costH1g = 4194304;   // per bg img
  size_t avail = (ws_size > fixed_end) ? ws_size - fixed_end : 0;
  int nb = (int)(avail / (costTb + costH1b));
  if (nb < 1) nb = 1;
  if (nb > 10) nb = 10;
  int ng = 1;
  for (int t = 10; t >= 1; --t) {
    size_t Tr = (size_t)nb * costTb; if ((size_t)t * costTg > Tr) Tr = (size_t)t * costTg;
    size_t Hr = (size_t)nb * costH1b; if ((size_t)t * costH1g > Hr) Hr = (size_t)t * costH1g;
    if (Tr + Hr <= avail) { ng = t; break; }
  }
  size_t Treg = (size_t)nb * costTb; if ((size_t)ng * costTg > Treg) Treg = (size_t)ng * costTg;
  unsigned short* Tbuf = (unsigned short*)(wsb + fixed_end);
  float* h1 = (float*)(wsb + fixed_end + Treg);
  const unsigned int psI = (unsigned int)(nb * 8 * 278784);   // elems/plane (capacity)
  const unsigned int psB = (unsigned int)(ng * 1081600);

  prep_w3<<<144, 256, 0, stream>>>(w1i, wBi3);
  prep_w3<<<144, 256, 0, stream>>>(w1b, wBb3);

  // ---- instance branch, chunks of nb b's (8 imgs per b)
  for (int b0 = 0; b0 < 10; b0 += nb) {
    int nbc = (10 - b0 < nb) ? (10 - b0) : nb;
    split_inst<<<1089 * nbc, 256, 0, stream>>>(IF + (size_t)b0 * 2097152, Tbuf, psI, nbc);
    conv1_dg<<<128 * nbc, 256, 0, stream>>>(Tbuf, psI, wBi3, b1i, h1, 64, 64, 66, 66);
    conv2_k<<<128 * nbc, 256, 0, stream>>>(h1, w2i, b2i, instw + (size_t)b0 * 32768,
                                           nbc * 8, 64, 64);
  }

  // ---- bg branch, chunks of ng imgs
  for (int i0 = 0; i0 < 10; i0 += ng) {
    int ngc = (10 - i0 < ng) ? (10 - i0) : ng;
    split_bg<<<4225 * ngc, 256, 0, stream>>>(BG + (size_t)i0 * 1048576, Tbuf, psB, ngc);
    conv1_dg<<<64 * ngc, 256, 0, stream>>>(Tbuf, psB, wBb3, b1b, h1, 128, 128, 130, 130);
    conv2_k<<<64 * ngc, 256, 0, stream>>>(h1, w2b, b2b, bgw + (size_t)i0 * 16384,
                                          ngc, 128, 128);
  }

  // ---- fused resize + softmax composition
  compose_k<<<40960, 256, 0, stream>>>(IF, BG, BBOX, objn, instw, bgw, out);
}

// Round 8
// 574.906 us; speedup vs baseline: 1.4795x; 1.4795x over previous
//
#include <hip/hip_runtime.h>
#include <cstdint>
#include <cstddef>

// B=10, Hi=Wi=64, C=64, M=8, Hb=Wb=128, U=64.
// conv1 = fp32-accurate MFMA implicit GEMM via 3-way bf16 split (6 products),
// LDS-staged A (split3 fused into staging, channel-half passes), register-
// reused B (64px-wide waves). h1 fp32 (rmask accuracy cliff). conv2/compose
// unchanged (proven since round 1/5).

typedef __attribute__((ext_vector_type(8))) short short8;
typedef __attribute__((ext_vector_type(4))) float f32x4;

__device__ __forceinline__ unsigned short f2bf(float x) {
  union { float f; unsigned int u; } v; v.f = x;
  unsigned int r = (v.u + 0x7FFFu + ((v.u >> 16) & 1u)) >> 16;  // RNE
  return (unsigned short)r;
}
__device__ __forceinline__ float bf2f(unsigned short h) {
  union { unsigned int u; float f; } v; v.u = ((unsigned int)h) << 16;
  return v.f;
}
__device__ __forceinline__ void split3(float v, unsigned short& h,
                                       unsigned short& m, unsigned short& l) {
  h = f2bf(v);
  float r1 = v - bf2f(h);
  m = f2bf(r1);
  float r2 = r1 - bf2f(m);
  l = f2bf(r2);
}

// ---------------------------------------------------------------------------
// prep_w3: w [3,3,64,64] HWIO fp32 -> 3 bf16 fragment-ordered planes (36864
// elems apart): wB[s][((kc*4+ut)*64+lane)*8+i], k=kc*32+(lane>>4)*8+i,
// k9=k>>6, c=k&63, u=ut*16+(lane&15).  (verified rounds 5/6/7)
// ---------------------------------------------------------------------------
__global__ void prep_w3(const float* __restrict__ w, unsigned short* __restrict__ wB)
{
  int idx = blockIdx.x * 256 + threadIdx.x;
  if (idx >= 18 * 4 * 64 * 8) return;
  int i = idx & 7;
  int lane = (idx >> 3) & 63;
  int ut = (idx >> 9) & 3;
  int kc = idx >> 11;
  int k = kc * 32 + (lane >> 4) * 8 + i;
  int u = ut * 16 + (lane & 15);
  int k9 = k >> 6, c = k & 63;
  float v = w[((size_t)(k9 * 64 + c)) * 64 + u];
  unsigned short h, m, l;
  split3(v, h, m, l);
  wB[idx] = h;
  wB[36864 + idx] = m;
  wB[73728 + idx] = l;
}

// ---------------------------------------------------------------------------
// conv1_ls: fp32 in (INST: strided gather from IF[B,64,64,64,8]; else NHWC)
// -> fp32 h1 [Nimg,H,W,64], 3x3 SAME + bias + relu.
// Block = 4 waves = 4 output rows x 64 px x 64 u; wave fragments: 4 pxt x 4 ut.
// Two passes over channel halves (pass cc <-> kc = 2*tap+cc, matching wB's
// k-layout c = (kc&1)*32 + g*8 + i). LDS per pass: 3 planes x 6 rows x 66 px
// x 32 ch bf16 = 76,032 B, layout [pl][row][c8][xi] (word-bank 8g+4xi: all
// 32 banks x 2-way = conflict-free for b128 reads AND writes).
// A-fragment/B-fragment/D-epilogue conventions byte-identical to the
// round-6/7-verified kernels.
// ---------------------------------------------------------------------------
template<bool INST>
__global__ __launch_bounds__(256, 2) void conv1_ls(const float* __restrict__ src,
    const unsigned short* __restrict__ wB, const float* __restrict__ bias,
    float* __restrict__ H1, int H, int W)
{
  __shared__ __align__(16) char lds[76032];   // 3 * 25344

  const int tid = threadIdx.x;
  const int tilesX = W >> 6;
  const int bid = blockIdx.x;
  const int xt = bid % tilesX;
  const int t2 = bid / tilesX;
  const int RG = H >> 2;
  const int rg = t2 % RG;
  const int img = t2 / RG;
  const int yb = rg << 2;
  const int xb = xt << 6;
  const int wave = tid >> 6, lane = tid & 63;
  const int mrow = lane & 15, g = lane >> 4;

  int b = 0, m = 0;
  if (INST) { b = img >> 3; m = img & 7; }

  f32x4 z = {0.f, 0.f, 0.f, 0.f};
  f32x4 acc[4][4];   // [pxt][ut]
  #pragma unroll
  for (int i = 0; i < 4; ++i)
    #pragma unroll
    for (int j = 0; j < 4; ++j)
      acc[i][j] = z;

  const short8* wBp = (const short8*)wB;   // plane stride 4608 short8

  for (int cc = 0; cc < 2; ++cc) {
    if (cc) __syncthreads();   // pass-0 readers done before overwrite
    // ---- stage + split: rows yb-1..yb+4, x xb-1..xb+64, 32-ch half
    for (int e = tid; e < 1584; e += 256) {
      const int c8 = e & 3;         // 8-ch granule within the half
      const int q = e >> 2;
      const int xi = q % 66;
      const int r = q / 66;         // 0..5 staged row
      const int gy = yb + r - 1;
      const int gx = xb + xi - 1;
      float v[8] = {0.f, 0.f, 0.f, 0.f, 0.f, 0.f, 0.f, 0.f};
      if (gy >= 0 && gy < H && gx >= 0 && gx < W) {
        if (INST) {
          const float* p = src + (size_t)b * 2097152 + (size_t)gy * 32768
                               + (size_t)gx * 512 + (size_t)(cc * 32 + c8 * 8) * 8 + m;
          #pragma unroll
          for (int j = 0; j < 8; ++j) v[j] = p[j * 8];
        } else {
          const float* p = src + ((size_t)(img * H + gy) * W + gx) * 64 + cc * 32 + c8 * 8;
          float4 a = *(const float4*)p;
          float4 bq = *(const float4*)(p + 4);
          v[0] = a.x; v[1] = a.y; v[2] = a.z; v[3] = a.w;
          v[4] = bq.x; v[5] = bq.y; v[6] = bq.z; v[7] = bq.w;
        }
      }
      short8 ph, pm, pl;
      #pragma unroll
      for (int j = 0; j < 8; ++j) {
        unsigned short h, mi, l;
        split3(v[j], h, mi, l);
        ph[j] = (short)h; pm[j] = (short)mi; pl[j] = (short)l;
      }
      const int wbase = (r * 4 + c8) * 1056 + xi * 16;
      *(short8*)&lds[wbase] = ph;
      *(short8*)&lds[wbase + 25344] = pm;
      *(short8*)&lds[wbase + 50688] = pl;
    }
    __syncthreads();

    // ---- K-loop over 9 taps (kc = 2*tap + cc)
    for (int tap = 0; tap < 9; ++tap) {
      const int dy = tap / 3, dx = tap % 3;
      const int kc = tap * 2 + cc;
      short8 a[4][3];
      #pragma unroll
      for (int pxt = 0; pxt < 4; ++pxt) {
        const int abase = ((wave + dy) * 4 + g) * 1056 + (pxt * 16 + mrow + dx) * 16;
        #pragma unroll
        for (int pl = 0; pl < 3; ++pl)
          a[pxt][pl] = *(const short8*)&lds[abase + pl * 25344];
      }
      #pragma unroll
      for (int ut = 0; ut < 4; ++ut) {
        const int bi = (kc * 4 + ut) * 64 + lane;
        short8 bh = wBp[bi];
        short8 bm = wBp[4608 + bi];
        short8 bl = wBp[9216 + bi];
        #pragma unroll
        for (int pxt = 0; pxt < 4; ++pxt) {
          f32x4 v4 = acc[pxt][ut];
          v4 = __builtin_amdgcn_mfma_f32_16x16x32_bf16(a[pxt][0], bh, v4, 0, 0, 0);
          v4 = __builtin_amdgcn_mfma_f32_16x16x32_bf16(a[pxt][0], bm, v4, 0, 0, 0);
          v4 = __builtin_amdgcn_mfma_f32_16x16x32_bf16(a[pxt][1], bh, v4, 0, 0, 0);
          v4 = __builtin_amdgcn_mfma_f32_16x16x32_bf16(a[pxt][0], bl, v4, 0, 0, 0);
          v4 = __builtin_amdgcn_mfma_f32_16x16x32_bf16(a[pxt][2], bh, v4, 0, 0, 0);
          v4 = __builtin_amdgcn_mfma_f32_16x16x32_bf16(a[pxt][1], bm, v4, 0, 0, 0);
          acc[pxt][ut] = v4;
        }
      }
    }
  }

  // ---- epilogue: D row=(lane>>4)*4+r (=px), col=lane&15 (=u); y = yb+wave
  const int y = yb + wave;
  #pragma unroll
  for (int ut = 0; ut < 4; ++ut) {
    const int u = ut * 16 + mrow;
    const float bv = bias[u];
    #pragma unroll
    for (int pxt = 0; pxt < 4; ++pxt) {
      #pragma unroll
      for (int r = 0; r < 4; ++r) {
        const int px = xb + pxt * 16 + g * 4 + r;
        H1[((size_t)(img * H + y) * W + px) * 64 + u] = fmaxf(acc[pxt][ut][r] + bv, 0.f);
      }
    }
  }
}

// ---------------------------------------------------------------------------
// conv2: 3x3 SAME, 64 -> 1 ch + bias + relu, fp32 (proven).
// ---------------------------------------------------------------------------
__global__ __launch_bounds__(256) void conv2_k(const float* __restrict__ hsrc,
    const float* __restrict__ w2, const float* __restrict__ b2,
    float* __restrict__ dst, int N, int H, int W)
{
  const int RS = 24;
  const int CS = 18 * 24 + 1;  // 433
  __shared__ float s[32 * (18 * 24 + 1)];
  __shared__ float wsm[576];

  const int tid = threadIdx.x;
  const int tilesX = W >> 4;
  const int bid = blockIdx.x;
  const int xt = bid % tilesX;
  const int q0 = bid / tilesX;
  const int yt = q0 % (H >> 4);
  const int n = q0 / (H >> 4);
  const int xb = xt << 4, yb = yt << 4;
  const int tx = tid & 15, ty = tid >> 4;

  for (int e = tid; e < 576; e += 256) wsm[e] = w2[e];

  float acc = 0.f;
  for (int cc = 0; cc < 2; ++cc) {
    const int c0 = cc << 5;
    if (cc) __syncthreads();
    for (int e = tid; e < 18 * 18 * 32; e += 256) {
      int c = e & 31;
      int p = e >> 5;
      int xx = p % 18;
      int yy = p / 18;
      int gy = yb + yy - 1, gx = xb + xx - 1;
      float v = 0.f;
      if (gy >= 0 && gy < H && gx >= 0 && gx < W)
        v = hsrc[((size_t)(n * H + gy) * W + gx) * 64 + c0 + c];
      s[c * CS + yy * RS + xx] = v;
    }
    __syncthreads();
    for (int c = 0; c < 32; ++c) {
      const float* sp = &s[c * CS + ty * RS + tx];
      const float* wp = &wsm[c0 + c];
      #pragma unroll
      for (int dy = 0; dy < 3; ++dy)
        #pragma unroll
        for (int dx = 0; dx < 3; ++dx)
          acc += sp[dy * RS + dx] * wp[(dy * 3 + dx) * 64];
    }
  }
  float bv = b2[0];
  dst[((size_t)n * H + yb + ty) * W + xb + tx] = fmaxf(acc + bv, 0.f);
}

// ---------------------------------------------------------------------------
// compose: fused resize_and_pad + masked-exp softmax composition (proven).
// ---------------------------------------------------------------------------
__global__ __launch_bounds__(256) void compose_k(const float* __restrict__ IF,
    const float* __restrict__ bg, const float* __restrict__ bbox,
    const int* __restrict__ objn, const float* __restrict__ instw,
    const float* __restrict__ bgw, float* __restrict__ out)
{
  const int tid = threadIdx.x;
  const int c = tid & 63;
  const int pid = blockIdx.x * 4 + (tid >> 6);
  const int b = pid >> 14;
  const int rem = pid & 16383;
  const int hh = rem >> 7;
  const int www = rem & 127;

  const float ebg = expf(bgw[pid]);
  const float bgc = bg[(size_t)pid * 64 + c];
  float acc = ebg * bgc;
  float denom = ebg;
  const int nobj = objn[b];

  #pragma unroll
  for (int m = 0; m < 8; ++m) {
    if (m >= nobj) continue;
    const float y0b = bbox[b * 32 + m];
    const float y1b = bbox[b * 32 + 8 + m];
    const float x0b = bbox[b * 32 + 16 + m];
    const float x1b = bbox[b * 32 + 24 + m];
    const float ysz = floorf(128.f * (y1b - y0b));
    const float xsz = floorf(128.f * (x1b - x0b));
    const float yf = floorf(128.f * y0b);
    const float xf = floorf(128.f * x0b);
    const float ly = (float)hh - yf;
    const float lx = (float)www - xf;
    if (!(ly >= 0.f && ly < ysz && lx >= 0.f && lx < xsz)) continue;
    float sy = (ly + 0.5f) * 64.f / fmaxf(ysz, 1.f) - 0.5f;
    float sx = (lx + 0.5f) * 64.f / fmaxf(xsz, 1.f) - 0.5f;
    sy = fminf(fmaxf(sy, 0.f), 63.f);
    sx = fminf(fmaxf(sx, 0.f), 63.f);
    const int y0i = (int)floorf(sy);
    const int x0i = (int)floorf(sx);
    const int y1i = min(y0i + 1, 63);
    const int x1i = min(x0i + 1, 63);
    const float wy = sy - (float)y0i;
    const float wx = sx - (float)x0i;
    const float omwx = 1.f - wx, omwy = 1.f - wy;

    const float* iw = instw + (size_t)(b * 8 + m) * 4096;
    const float v00 = iw[y0i * 64 + x0i];
    const float v01 = iw[y0i * 64 + x1i];
    const float v10 = iw[y1i * 64 + x0i];
    const float v11 = iw[y1i * 64 + x1i];
    const float rwv = (v00 * omwx + v01 * wx) * omwy + (v10 * omwx + v11 * wx) * wy;
    if (!(rwv > 0.f)) continue;
    const float e = expf(rwv);
    denom += e;

    const float* fb = IF + (size_t)b * 2097152 + (size_t)c * 8 + m;
    const float t00 = fb[(size_t)y0i * 32768 + (size_t)x0i * 512];
    const float t01 = fb[(size_t)y0i * 32768 + (size_t)x1i * 512];
    const float t10 = fb[(size_t)y1i * 32768 + (size_t)x0i * 512];
    const float t11 = fb[(size_t)y1i * 32768 + (size_t)x1i * 512];
    const float bil = (t00 * omwx + t01 * wx) * omwy + (t10 * omwx + t11 * wx) * wy;
    acc += e * bil;
  }
  out[(size_t)pid * 64 + c] = acc / denom;
}

// ---------------------------------------------------------------------------
extern "C" void kernel_launch(void* const* d_in, const int* in_sizes, int n_in,
                              void* d_out, int out_size, void* d_ws, size_t ws_size,
                              hipStream_t stream)
{
  const float* IF   = (const float*)d_in[0];   // [10,64,64,64,8]
  const float* BG   = (const float*)d_in[1];   // [10,128,128,64]
  const float* BBOX = (const float*)d_in[2];   // [10,4,8]
  const float* w1i = (const float*)d_in[4];
  const float* b1i = (const float*)d_in[5];
  const float* w2i = (const float*)d_in[6];
  const float* b2i = (const float*)d_in[7];
  const float* w1b = (const float*)d_in[8];
  const float* b1b = (const float*)d_in[9];
  const float* w2b = (const float*)d_in[10];
  const float* b2b = (const float*)d_in[11];
  const int* objn  = (const int*)d_in[12];
  float* out = (float*)d_out;

  char* wsb = (char*)d_ws;
  unsigned short* wBi3 = (unsigned short*)(wsb);              // 221,184 B
  unsigned short* wBb3 = (unsigned short*)(wsb + 221184);     // 221,184 B
  float* instw = (float*)(wsb + 442368);                      // 1,310,720 B
  float* bgw   = (float*)(wsb + 1753088);                     // 655,360 B
  float* h1    = (float*)(wsb + 2408448);                     // 83,886,080 B -> 86.3 MB

  prep_w3<<<144, 256, 0, stream>>>(w1i, wBi3);
  prep_w3<<<144, 256, 0, stream>>>(w1b, wBb3);

  // instance branch: conv1 (fused gather + split) -> conv2
  conv1_ls<true><<<80 * 16, 256, 0, stream>>>(IF, wBi3, b1i, h1, 64, 64);
  conv2_k<<<80 * 4 * 4, 256, 0, stream>>>(h1, w2i, b2i, instw, 80, 64, 64);

  // bg branch (reuses h1)
  conv1_ls<false><<<10 * 32 * 2, 256, 0, stream>>>(BG, wBb3, b1b, h1, 128, 128);
  conv2_k<<<10 * 8 * 8, 256, 0, stream>>>(h1, w2b, b2b, bgw, 10, 128, 128);

  // fused resize + softmax composition
  compose_k<<<40960, 256, 0, stream>>>(IF, BG, BBOX, objn, instw, bgw, out);
}